// Round 16
// baseline (541.209 us; speedup 1.0000x reference)
//
#include <hip/hip_runtime.h>

typedef short bf16x8 __attribute__((ext_vector_type(8)));
typedef float f32x4 __attribute__((ext_vector_type(4)));

#define NROWS 131072L
#define DIN 1024
#define DEMB 512
#define NEXT 640   // extended B rows: 512 emb + 34 folded-head + zero tail

__device__ __forceinline__ unsigned short f2bf(float f) {
  unsigned u = __float_as_uint(f);
  u += 0x7FFFu + ((u >> 16) & 1u);
  return (unsigned short)(u >> 16);
}

// Pack two f32 -> two bf16 (round-half-up): 2 adds + 1 v_perm_b32 (R5+-proven).
__device__ __forceinline__ unsigned pkhi(float a, float b) {
  unsigned ua = __float_as_uint(a) + 0x8000u;
  unsigned ub = __float_as_uint(b) + 0x8000u;
  return __builtin_amdgcn_perm(ub, ua, 0x07060302u);
}

__device__ __forceinline__ float softplusf(float v) {
  return fmaxf(v, 0.f) + log1pf(expf(-fabsf(v)));
}

// ---------- kernel 0: Wb (1024x512 f32) -> WbT rows 0..511 (bf16, k-contig) ----------
__global__ __launch_bounds__(256) void wb_transpose(const float* __restrict__ Wb,
                                                    unsigned short* __restrict__ WbT) {
  int g = blockIdx.x * 256 + threadIdx.x;
  int n = g & 511;
  int kb = g >> 9;
  unsigned short tmp[8];
#pragma unroll
  for (int j = 0; j < 8; ++j)
    tmp[j] = f2bf(Wb[(kb * 8 + j) * DEMB + n]);
  uint4 v;
  v.x = (unsigned)tmp[0] | ((unsigned)tmp[1] << 16);
  v.y = (unsigned)tmp[2] | ((unsigned)tmp[3] << 16);
  v.z = (unsigned)tmp[4] | ((unsigned)tmp[5] << 16);
  v.w = (unsigned)tmp[6] | ((unsigned)tmp[7] << 16);
  *(uint4*)(WbT + (long)n * DIN + kb * 8) = v;
}

// ---------- kernel 0b: zero rows 546..639 of WbT_ext ----------
__global__ void zero_tail(unsigned* __restrict__ p) {
  p[blockIdx.x * 256 + threadIdx.x] = 0u;
}

// ---------- kernel 0c: WbT rows 512..545 = (Wb @ W34)^T ----------
__global__ __launch_bounds__(256) void wfold_rows(const float* __restrict__ Wb,
                                                  const float* __restrict__ Wp,
                                                  const float* __restrict__ Ws,
                                                  unsigned short* __restrict__ WbT) {
  int w = threadIdx.x >> 6, lane = threadIdx.x & 63;
  int k = blockIdx.x * 4 + w;
  if (lane >= 34) return;
  const float* src;
  if (lane < 2) src = Wp + lane;
  else { int s = (lane - 2) >> 1; src = Ws + s * 1024 + (lane & 1); }
  const float* wrow = Wb + (long)k * DEMB;
  float acc = 0.f;
#pragma unroll 8
  for (int d = 0; d < DEMB; ++d) acc = fmaf(wrow[d], src[2 * d], acc);
  WbT[(long)(512 + lane) * DIN + k] = f2bf(acc);
}

// ---------- kernel 0d: bfold[j] = bb @ W34[:,j] + bias34[j] ----------
__global__ void bfold_k(const float* __restrict__ bb, const float* __restrict__ Wp,
                        const float* __restrict__ bp, const float* __restrict__ Ws,
                        const float* __restrict__ bs, float* __restrict__ bf) {
  int j = threadIdx.x;
  if (j >= 34) return;
  const float* src; float bias;
  if (j < 2) { src = Wp + j; bias = bp[j]; }
  else { int s = (j - 2) >> 1; src = Ws + s * 1024 + (j & 1); bias = bs[s * 2 + (j & 1)]; }
  float acc = bias;
  for (int d = 0; d < DEMB; ++d) acc = fmaf(bb[d], src[2 * d], acc);
  bf[j] = acc;
}

#define SB __builtin_amdgcn_sched_barrier(0)

// ---------- kernel 1: fused GEMM — BM=512 BN=128 BK=64, wave-tile 128x64 ----------
// LDS-BW fix: 8 waves (4m x 2n), acc 8x4. LDS bytes/MAC drops 62.5 -> 46.9
// B/KMAC and staging amortizes over 2x MACs. A staged in two half-rounds
// (8 float4 live regs, no spill). LDS 160KB (full pool), 1 block/CU.
__global__ __launch_bounds__(512, 2) void gemm_fused(
    const float* __restrict__ x, const unsigned short* __restrict__ wbt,
    const float* __restrict__ bb, const int* __restrict__ sid,
    const float* __restrict__ bfold, float* __restrict__ out) {
  __shared__ __align__(16) char SM[163840];  // As0|As1 (64K ea) | Bs0|Bs1 (16K ea)
  char* const As0 = SM;
  char* const As1 = SM + 65536;
  char* const Bs0 = SM + 131072;
  char* const Bs1 = SM + 147456;

  const int t = threadIdx.x;                 // 0..511
  const int lane = t & 63;
  const int wid = t >> 6;                    // 0..7
  const int wm = wid >> 1, wn = wid & 1;     // 4m x 2n

  // XCD swizzle: 1280 blocks (%8==0); 5 consecutive swz share one mtile/XCD.
  const int bid = blockIdx.x;
  const int swz = (bid & 7) * 160 + (bid >> 3);
  const int mtile = swz / 5;
  const int ntile = swz - mtile * 5;         // 0..3 emb, 4 = head
  const long m0 = (long)mtile * 512;
  const int n0 = ntile * 128;

  // ---- A staging (R13 algebra): row = t>>4 (+p*32, p 0..15), float4-col t&15 ----
  const int arow = t >> 4;
  const int abyte = arow * 128 + (((t & 15) * 8) ^ ((arow & 7) << 4));   // +p*4096
  const float* xbase = x + (m0 + arow) * DIN + (t & 15) * 4;

  // ---- B staging (R13 algebra, 512 threads): 2 gload_lds/thread ----
  const int bg = (t & 7) ^ ((t >> 3) & 7);
  const unsigned short* bsrc = wbt + (long)(n0 + (t >> 3)) * DIN + bg * 8;
  const int bdst = t * 16;                   // + i*8192 (rows i*64 + (t>>3))

  // ---- fragment reads (R13-verbatim): granule (ks*4+lg) ^ (l15&7), 128B rows ----
  const int l15 = lane & 15, lg = lane >> 4;
  const int s3 = lane & 7;
  const int kg0 = ((lg ^ s3) << 4);          // ks=1 -> ^64
  const int ardrow = (wm * 128 + l15) * 128; // + mi*2048, mi 0..7
  const int brdrow = (wn * 64 + l15) * 128;  // + ni*2048, ni 0..3

  f32x4 acc[8][4] = {};
  float4 aR[8];                              // half-tile A reg buffer

  auto loadA8 = [&](int k0, int h) {         // 8 x dwordx4, rows h*256..+255
#pragma unroll
    for (int j = 0; j < 8; ++j)
      aR[j] = *(const float4*)(xbase + (long)(h * 8 + j) * 32 * DIN + k0);
  };
  auto stageB = [&](char* Bw, int k0) {      // 2 x gload_lds 16B
#pragma unroll
    for (int i = 0; i < 2; ++i) {
      const unsigned short* gp = bsrc + (long)i * 64 * DIN + k0;
      __builtin_amdgcn_global_load_lds(
          (const __attribute__((address_space(1))) void*)gp,
          (__attribute__((address_space(3))) void*)(Bw + i * 8192 + bdst),
          16, 0, 0);
    }
  };
  auto writeA8 = [&](char* Aw, int h) {      // 8 x ds_write_b64 (pkhi)
#pragma unroll
    for (int j = 0; j < 8; ++j) {
      uint2 v;
      v.x = pkhi(aR[j].x, aR[j].y);
      v.y = pkhi(aR[j].z, aR[j].w);
      *(uint2*)(Aw + abyte + (h * 8 + j) * 4096) = v;
    }
  };
  auto compute_ks = [&](const char* Ac, const char* Bc, int ks) {  // 12 b128 + 32 MFMA
    const int kgo = kg0 ^ (ks << 6);
    bf16x8 af[8], bfv[4];
#pragma unroll
    for (int i = 0; i < 8; ++i)
      af[i] = *(const bf16x8*)(Ac + ardrow + i * 2048 + kgo);
#pragma unroll
    for (int i = 0; i < 4; ++i)
      bfv[i] = *(const bf16x8*)(Bc + brdrow + i * 2048 + kgo);
    __builtin_amdgcn_s_setprio(1);
#pragma unroll
    for (int mi = 0; mi < 8; ++mi)
#pragma unroll
      for (int ni = 0; ni < 4; ++ni)
        acc[mi][ni] = __builtin_amdgcn_mfma_f32_16x16x32_bf16(af[mi], bfv[ni],
                                                             acc[mi][ni], 0, 0, 0);
    __builtin_amdgcn_s_setprio(0);
  };

  // phase t: A(t+1) half0 loads; B(t+1); compute ks0(t); wait half0; write half0;
  //          A(t+1) half1 loads; compute ks1(t); wait all; write half1; barrier.
#define PH(AC, BC, AW, BW, TT)                                      \
  loadA8(((TT) + 1) * 64, 0);                                       \
  stageB(BW, ((TT) + 1) * 64);                                      \
  compute_ks(AC, BC, 0);                                            \
  SB; asm volatile("s_waitcnt vmcnt(2)" ::: "memory"); SB;          \
  writeA8(AW, 0);                                                   \
  loadA8(((TT) + 1) * 64, 1);                                       \
  compute_ks(AC, BC, 1);                                            \
  SB; asm volatile("s_waitcnt vmcnt(0)" ::: "memory"); SB;          \
  writeA8(AW, 1);                                                   \
  SB; asm volatile("s_waitcnt lgkmcnt(0)" ::: "memory"); SB;        \
  __builtin_amdgcn_s_barrier();

  // ---- prologue: tile 0 staged+written ----
  loadA8(0, 0);
  stageB(Bs0, 0);
  SB; asm volatile("s_waitcnt vmcnt(2)" ::: "memory"); SB;   // half0 landed (B flying)
  writeA8(As0, 0);
  loadA8(0, 1);
  SB; asm volatile("s_waitcnt vmcnt(2)" ::: "memory"); SB;   // half1 landed (B flying)
  writeA8(As0, 1);
  SB; asm volatile("s_waitcnt vmcnt(0) lgkmcnt(0)" ::: "memory"); SB;
  __builtin_amdgcn_s_barrier();

  // ---- main loop: phases 0..13 (pairs), phase 14, tail 15 ----
#pragma unroll 1
  for (int tb = 0; tb < 14; tb += 2) {
    PH(As0, Bs0, As1, Bs1, tb + 0)
    PH(As1, Bs1, As0, Bs0, tb + 1)
  }
  PH(As0, Bs0, As1, Bs1, 14)
#undef PH
  compute_ks(As1, Bs1, 0);                   // tile 15
  compute_ks(As1, Bs1, 1);

  // ---- epilogue ----
  if (ntile < 4) {
    const int colg = n0 + wn * 64 + l15;
    float bbv[4];
#pragma unroll
    for (int ni = 0; ni < 4; ++ni) bbv[ni] = bb[colg + ni * 16];
#pragma unroll
    for (int mi = 0; mi < 8; ++mi) {
      const long rbase = m0 + wm * 128 + mi * 16 + lg * 4;
#pragma unroll
      for (int ni = 0; ni < 4; ++ni)
#pragma unroll
        for (int r = 0; r < 4; ++r)
          out[(rbase + r) * DEMB + colg + ni * 16] = acc[mi][ni][r] + bbv[ni];
    }
  } else {
    // head tile: acc cols 0..33 are x@Wfold; gather per-row selected cols via LDS
    __syncthreads();
    float* hl = (float*)SM;                  // [512][35] f32 = 71.7 KB overlay
    if (wn == 0) {
#pragma unroll
      for (int ni = 0; ni < 3; ++ni) {
#pragma unroll
        for (int mi = 0; mi < 8; ++mi)
#pragma unroll
          for (int r = 0; r < 4; ++r) {
            int row = wm * 128 + mi * 16 + lg * 4 + r;
            int col = l15 + ni * 16;
            if (col < 35) hl[row * 35 + col] = acc[mi][ni][r];
          }
      }
    }
    __syncthreads();
    {
      const long row = m0 + t;
      const int s = sid[row];
      const float v0 = hl[t * 35 + 0] + bfold[0];
      const float v1 = hl[t * 35 + 1] + bfold[1];
      const float v2 = hl[t * 35 + 2 + 2 * s] + bfold[2 + 2 * s];
      const float v3 = hl[t * 35 + 3 + 2 * s] + bfold[3 + 2 * s];
      float* hp = out + NROWS * DEMB;
      hp[row] = v0;
      hp[NROWS + row] = softplusf(v1) + 0.001f;
      hp[2 * NROWS + row] = v2;
      hp[3 * NROWS + row] = softplusf(v3) + 0.001f;
    }
  }
}

extern "C" void kernel_launch(void* const* d_in, const int* in_sizes, int n_in,
                              void* d_out, int out_size, void* d_ws, size_t ws_size,
                              hipStream_t stream) {
  const float* x  = (const float*)d_in[0];
  const int* sid  = (const int*)d_in[1];
  const float* Wb = (const float*)d_in[2];
  const float* bb = (const float*)d_in[3];
  const float* Wp = (const float*)d_in[4];
  const float* bp = (const float*)d_in[5];
  const float* Ws = (const float*)d_in[6];
  const float* bs = (const float*)d_in[7];
  float* out = (float*)d_out;
  unsigned short* WbT = (unsigned short*)d_ws;            // 640*1024 bf16 = 1.25 MiB
  float* bfoldp = (float*)(WbT + (long)NEXT * DIN);       // 34 f32

  wb_transpose<<<256, 256, 0, stream>>>(Wb, WbT);
  zero_tail<<<188, 256, 0, stream>>>((unsigned*)(WbT + 546 * DIN));
  wfold_rows<<<256, 256, 0, stream>>>(Wb, Wp, Ws, WbT);
  bfold_k<<<1, 64, 0, stream>>>(bb, Wp, bp, Ws, bs, bfoldp);
  gemm_fused<<<1280, 512, 0, stream>>>(x, WbT, bb, sid, bfoldp, out);
}

// Round 17
// 378.051 us; speedup vs baseline: 1.4316x; 1.4316x over previous
//
#include <hip/hip_runtime.h>

typedef short bf16x8 __attribute__((ext_vector_type(8)));
typedef float f32x4 __attribute__((ext_vector_type(4)));

#define NROWS 131072L
#define DIN 1024
#define DEMB 512
#define NEXT 640   // extended B rows: 512 emb + 34 folded-head + zero tail

__device__ __forceinline__ unsigned short f2bf(float f) {
  unsigned u = __float_as_uint(f);
  u += 0x7FFFu + ((u >> 16) & 1u);
  return (unsigned short)(u >> 16);
}

// Pack two f32 -> two bf16 (round-half-up): 2 adds + 1 v_perm_b32 (R5+-proven).
__device__ __forceinline__ unsigned pkhi(float a, float b) {
  unsigned ua = __float_as_uint(a) + 0x8000u;
  unsigned ub = __float_as_uint(b) + 0x8000u;
  return __builtin_amdgcn_perm(ub, ua, 0x07060302u);
}

__device__ __forceinline__ float softplusf(float v) {
  return fmaxf(v, 0.f) + log1pf(expf(-fabsf(v)));
}

// ---------- kernel 0: Wb (1024x512 f32) -> WbT rows 0..511 (bf16, k-contig) ----------
__global__ __launch_bounds__(256) void wb_transpose(const float* __restrict__ Wb,
                                                    unsigned short* __restrict__ WbT) {
  int g = blockIdx.x * 256 + threadIdx.x;
  int n = g & 511;
  int kb = g >> 9;
  unsigned short tmp[8];
#pragma unroll
  for (int j = 0; j < 8; ++j)
    tmp[j] = f2bf(Wb[(kb * 8 + j) * DEMB + n]);
  uint4 v;
  v.x = (unsigned)tmp[0] | ((unsigned)tmp[1] << 16);
  v.y = (unsigned)tmp[2] | ((unsigned)tmp[3] << 16);
  v.z = (unsigned)tmp[4] | ((unsigned)tmp[5] << 16);
  v.w = (unsigned)tmp[6] | ((unsigned)tmp[7] << 16);
  *(uint4*)(WbT + (long)n * DIN + kb * 8) = v;
}

// ---------- kernel 0b: zero rows 546..639 of WbT_ext ----------
__global__ void zero_tail(unsigned* __restrict__ p) {
  p[blockIdx.x * 256 + threadIdx.x] = 0u;
}

// ---------- kernel 0c: WbT rows 512..545 = (Wb @ W34)^T ----------
__global__ __launch_bounds__(256) void wfold_rows(const float* __restrict__ Wb,
                                                  const float* __restrict__ Wp,
                                                  const float* __restrict__ Ws,
                                                  unsigned short* __restrict__ WbT) {
  int w = threadIdx.x >> 6, lane = threadIdx.x & 63;
  int k = blockIdx.x * 4 + w;
  if (lane >= 34) return;
  const float* src;
  if (lane < 2) src = Wp + lane;
  else { int s = (lane - 2) >> 1; src = Ws + s * 1024 + (lane & 1); }
  const float* wrow = Wb + (long)k * DEMB;
  float acc = 0.f;
#pragma unroll 8
  for (int d = 0; d < DEMB; ++d) acc = fmaf(wrow[d], src[2 * d], acc);
  WbT[(long)(512 + lane) * DIN + k] = f2bf(acc);
}

// ---------- kernel 0d: bfold[j] = bb @ W34[:,j] + bias34[j] ----------
__global__ void bfold_k(const float* __restrict__ bb, const float* __restrict__ Wp,
                        const float* __restrict__ bp, const float* __restrict__ Ws,
                        const float* __restrict__ bs, float* __restrict__ bf) {
  int j = threadIdx.x;
  if (j >= 34) return;
  const float* src; float bias;
  if (j < 2) { src = Wp + j; bias = bp[j]; }
  else { int s = (j - 2) >> 1; src = Ws + s * 1024 + (j & 1); bias = bs[s * 2 + (j & 1)]; }
  float acc = bias;
  for (int d = 0; d < DEMB; ++d) acc = fmaf(bb[d], src[2 * d], acc);
  bf[j] = acc;
}

#define SB __builtin_amdgcn_sched_barrier(0)

// ---------- kernel 1: fused GEMM — BM=512 BN=128 BK=64, wave-tile 128x64 ----------
// R16 geometry + R14 register discipline: ONE aR[8] staging buffer, two
// half-rounds per phase; af liveness 4 (two mi-half MFMA chunks). Peak regs
// ~222 unified (no spill). LDS 160KB full pool: As dbuf 2x64K, Bs dbuf 2x16K.
__global__ __launch_bounds__(512, 2) void gemm_fused(
    const float* __restrict__ x, const unsigned short* __restrict__ wbt,
    const float* __restrict__ bb, const int* __restrict__ sid,
    const float* __restrict__ bfold, float* __restrict__ out) {
  __shared__ __align__(16) char SM[163840];  // As0|As1 (64K ea) | Bs0|Bs1 (16K ea)
  char* const As0 = SM;
  char* const As1 = SM + 65536;
  char* const Bs0 = SM + 131072;
  char* const Bs1 = SM + 147456;

  const int t = threadIdx.x;                 // 0..511
  const int lane = t & 63;
  const int wid = t >> 6;                    // 0..7
  const int wm = wid >> 1, wn = wid & 1;     // 4m x 2n

  // XCD swizzle: 1280 blocks (%8==0); 5 consecutive swz share one mtile/XCD.
  const int bid = blockIdx.x;
  const int swz = (bid & 7) * 160 + (bid >> 3);
  const int mtile = swz / 5;
  const int ntile = swz - mtile * 5;         // 0..3 emb, 4 = head
  const long m0 = (long)mtile * 512;
  const int n0 = ntile * 128;

  // ---- A staging (R13 algebra): row = t>>4 (+p*32, p 0..15), float4-col t&15 ----
  const int arow = t >> 4;
  const int abyte = arow * 128 + (((t & 15) * 8) ^ ((arow & 7) << 4));   // +p*4096
  const float* xbase = x + (m0 + arow) * DIN + (t & 15) * 4;

  // ---- B staging (R13 algebra, 512 threads): 2 gload_lds/thread ----
  const int bg = (t & 7) ^ ((t >> 3) & 7);
  const unsigned short* bsrc = wbt + (long)(n0 + (t >> 3)) * DIN + bg * 8;
  const int bdst = t * 16;                   // + i*8192 (rows i*64 + (t>>3))

  // ---- fragment reads (R13-verbatim): granule (ks*4+lg) ^ (l15&7), 128B rows ----
  const int l15 = lane & 15, lg = lane >> 4;
  const int kg0 = ((lg ^ (l15 & 7)) << 4);   // ks=1 -> ^64
  const int ardrow = (wm * 128 + l15) * 128; // + mi*2048, mi 0..7
  const int brdrow = (wn * 64 + l15) * 128;  // + ni*2048, ni 0..3

  f32x4 acc[8][4] = {};
  float4 aR[8];                              // single half-tile staging buffer

  auto loadA8 = [&](int k0, int h) {         // 8 x dwordx4, rows (h*8+j)*32
#pragma unroll
    for (int j = 0; j < 8; ++j)
      aR[j] = *(const float4*)(xbase + (long)(h * 8 + j) * 32 * DIN + k0);
  };
  auto stageB = [&](char* Bw, int k0) {      // 2 x gload_lds 16B
#pragma unroll
    for (int i = 0; i < 2; ++i) {
      const unsigned short* gp = bsrc + (long)i * 64 * DIN + k0;
      __builtin_amdgcn_global_load_lds(
          (const __attribute__((address_space(1))) void*)gp,
          (__attribute__((address_space(3))) void*)(Bw + i * 8192 + bdst),
          16, 0, 0);
    }
  };
  auto writeA8 = [&](char* Aw, int h) {      // 8 x ds_write_b64 (pkhi)
#pragma unroll
    for (int j = 0; j < 8; ++j) {
      uint2 v;
      v.x = pkhi(aR[j].x, aR[j].y);
      v.y = pkhi(aR[j].z, aR[j].w);
      *(uint2*)(Aw + abyte + (h * 8 + j) * 4096) = v;
    }
  };
  auto compute_ks = [&](const char* Ac, const char* Bc, int ks) {
    const int kgo = kg0 ^ (ks << 6);
    bf16x8 bfv[4], af[4];
#pragma unroll
    for (int i = 0; i < 4; ++i)
      bfv[i] = *(const bf16x8*)(Bc + brdrow + i * 2048 + kgo);
    // mi-half 0
#pragma unroll
    for (int i = 0; i < 4; ++i)
      af[i] = *(const bf16x8*)(Ac + ardrow + i * 2048 + kgo);
    SB; asm volatile("s_waitcnt lgkmcnt(0)" ::: "memory"); SB;
    __builtin_amdgcn_s_setprio(1);
#pragma unroll
    for (int mi = 0; mi < 4; ++mi)
#pragma unroll
      for (int ni = 0; ni < 4; ++ni)
        acc[mi][ni] = __builtin_amdgcn_mfma_f32_16x16x32_bf16(af[mi], bfv[ni],
                                                             acc[mi][ni], 0, 0, 0);
    __builtin_amdgcn_s_setprio(0);
    // mi-half 1
#pragma unroll
    for (int i = 0; i < 4; ++i)
      af[i] = *(const bf16x8*)(Ac + ardrow + (i + 4) * 2048 + kgo);
    SB; asm volatile("s_waitcnt lgkmcnt(0)" ::: "memory"); SB;
    __builtin_amdgcn_s_setprio(1);
#pragma unroll
    for (int mi = 0; mi < 4; ++mi)
#pragma unroll
      for (int ni = 0; ni < 4; ++ni)
        acc[mi + 4][ni] = __builtin_amdgcn_mfma_f32_16x16x32_bf16(af[mi], bfv[ni],
                                                                 acc[mi + 4][ni], 0, 0, 0);
    __builtin_amdgcn_s_setprio(0);
  };

  // phase t: A-half0(t+1) + B(t+1) issued; ks0(t); vmcnt(2) [A-half0 done,
  // B stays]; write half0; A-half1 issued; ks1(t); vmcnt(0) [B ~2000cyc old,
  // free]; write half1; lgkm0; barrier.
#define PH(AC, BC, AW, BW, TT)                                      \
  loadA8(((TT) + 1) * 64, 0);                                       \
  stageB(BW, ((TT) + 1) * 64);                                      \
  compute_ks(AC, BC, 0);                                            \
  SB; asm volatile("s_waitcnt vmcnt(2)" ::: "memory"); SB;          \
  writeA8(AW, 0);                                                   \
  loadA8(((TT) + 1) * 64, 1);                                       \
  compute_ks(AC, BC, 1);                                            \
  SB; asm volatile("s_waitcnt vmcnt(0)" ::: "memory"); SB;          \
  writeA8(AW, 1);                                                   \
  SB; asm volatile("s_waitcnt lgkmcnt(0)" ::: "memory"); SB;        \
  __builtin_amdgcn_s_barrier();

  // ---- prologue: tile 0 staged+written ----
  loadA8(0, 0);
  stageB(Bs0, 0);
  SB; asm volatile("s_waitcnt vmcnt(2)" ::: "memory"); SB;
  writeA8(As0, 0);
  loadA8(0, 1);
  SB; asm volatile("s_waitcnt vmcnt(0)" ::: "memory"); SB;
  writeA8(As0, 1);
  SB; asm volatile("s_waitcnt lgkmcnt(0)" ::: "memory"); SB;
  __builtin_amdgcn_s_barrier();

  // ---- main loop: phases 0..13 (pairs), phase 14, tail tile 15 ----
#pragma unroll 1
  for (int tb = 0; tb < 14; tb += 2) {
    PH(As0, Bs0, As1, Bs1, tb + 0)
    PH(As1, Bs1, As0, Bs0, tb + 1)
  }
  PH(As0, Bs0, As1, Bs1, 14)
#undef PH
  compute_ks(As1, Bs1, 0);                   // tile 15
  compute_ks(As1, Bs1, 1);

  // ---- epilogue ----
  if (ntile < 4) {
    const int colg = n0 + wn * 64 + l15;
    float bbv[4];
#pragma unroll
    for (int ni = 0; ni < 4; ++ni) bbv[ni] = bb[colg + ni * 16];
#pragma unroll
    for (int mi = 0; mi < 8; ++mi) {
      const long rbase = m0 + wm * 128 + mi * 16 + lg * 4;
#pragma unroll
      for (int ni = 0; ni < 4; ++ni)
#pragma unroll
        for (int r = 0; r < 4; ++r)
          out[(rbase + r) * DEMB + colg + ni * 16] = acc[mi][ni][r] + bbv[ni];
    }
  } else {
    // head tile: acc cols 0..33 are x@Wfold; gather per-row selected cols via LDS
    __syncthreads();
    float* hl = (float*)SM;                  // [512][35] f32 = 71.7 KB overlay
    if (wn == 0) {
#pragma unroll
      for (int ni = 0; ni < 3; ++ni) {
#pragma unroll
        for (int mi = 0; mi < 8; ++mi)
#pragma unroll
          for (int r = 0; r < 4; ++r) {
            int row = wm * 128 + mi * 16 + lg * 4 + r;
            int col = l15 + ni * 16;
            if (col < 35) hl[row * 35 + col] = acc[mi][ni][r];
          }
      }
    }
    __syncthreads();
    {
      const long row = m0 + t;
      const int s = sid[row];
      const float v0 = hl[t * 35 + 0] + bfold[0];
      const float v1 = hl[t * 35 + 1] + bfold[1];
      const float v2 = hl[t * 35 + 2 + 2 * s] + bfold[2 + 2 * s];
      const float v3 = hl[t * 35 + 3 + 2 * s] + bfold[3 + 2 * s];
      float* hp = out + NROWS * DEMB;
      hp[row] = v0;
      hp[NROWS + row] = softplusf(v1) + 0.001f;
      hp[2 * NROWS + row] = v2;
      hp[3 * NROWS + row] = softplusf(v3) + 0.001f;
    }
  }
}

extern "C" void kernel_launch(void* const* d_in, const int* in_sizes, int n_in,
                              void* d_out, int out_size, void* d_ws, size_t ws_size,
                              hipStream_t stream) {
  const float* x  = (const float*)d_in[0];
  const int* sid  = (const int*)d_in[1];
  const float* Wb = (const float*)d_in[2];
  const float* bb = (const float*)d_in[3];
  const float* Wp = (const float*)d_in[4];
  const float* bp = (const float*)d_in[5];
  const float* Ws = (const float*)d_in[6];
  const float* bs = (const float*)d_in[7];
  float* out = (float*)d_out;
  unsigned short* WbT = (unsigned short*)d_ws;            // 640*1024 bf16 = 1.25 MiB
  float* bfoldp = (float*)(WbT + (long)NEXT * DIN);       // 34 f32

  wb_transpose<<<256, 256, 0, stream>>>(Wb, WbT);
  zero_tail<<<188, 256, 0, stream>>>((unsigned*)(WbT + 546 * DIN));
  wfold_rows<<<256, 256, 0, stream>>>(Wb, Wp, Ws, WbT);
  bfold_k<<<1, 64, 0, stream>>>(bb, Wp, bp, Ws, bs, bfoldp);
  gemm_fused<<<1280, 512, 0, stream>>>(x, WbT, bb, sid, bfoldp, out);
}

// Round 18
// 350.776 us; speedup vs baseline: 1.5429x; 1.0778x over previous
//
#include <hip/hip_runtime.h>

typedef short bf16x8 __attribute__((ext_vector_type(8)));
typedef float f32x4 __attribute__((ext_vector_type(4)));

#define NROWS 131072L
#define DIN 1024
#define DEMB 512
#define NEXT 640   // extended B rows: 512 emb + 34 folded-head + zero tail

__device__ __forceinline__ unsigned short f2bf(float f) {
  unsigned u = __float_as_uint(f);
  u += 0x7FFFu + ((u >> 16) & 1u);
  return (unsigned short)(u >> 16);
}

// Pack two f32 -> two bf16 (round-half-up): 2 adds + 1 v_perm_b32 (R5+-proven).
__device__ __forceinline__ unsigned pkhi(float a, float b) {
  unsigned ua = __float_as_uint(a) + 0x8000u;
  unsigned ub = __float_as_uint(b) + 0x8000u;
  return __builtin_amdgcn_perm(ub, ua, 0x07060302u);
}

__device__ __forceinline__ float softplusf(float v) {
  return fmaxf(v, 0.f) + log1pf(expf(-fabsf(v)));
}

// ---------- kernel 0: Wb (1024x512 f32) -> WbT rows 0..511 (bf16, k-contig) ----------
__global__ __launch_bounds__(256) void wb_transpose(const float* __restrict__ Wb,
                                                    unsigned short* __restrict__ WbT) {
  int g = blockIdx.x * 256 + threadIdx.x;
  int n = g & 511;
  int kb = g >> 9;
  unsigned short tmp[8];
#pragma unroll
  for (int j = 0; j < 8; ++j)
    tmp[j] = f2bf(Wb[(kb * 8 + j) * DEMB + n]);
  uint4 v;
  v.x = (unsigned)tmp[0] | ((unsigned)tmp[1] << 16);
  v.y = (unsigned)tmp[2] | ((unsigned)tmp[3] << 16);
  v.z = (unsigned)tmp[4] | ((unsigned)tmp[5] << 16);
  v.w = (unsigned)tmp[6] | ((unsigned)tmp[7] << 16);
  *(uint4*)(WbT + (long)n * DIN + kb * 8) = v;
}

// ---------- kernel 0b: zero rows 546..639 of WbT_ext ----------
__global__ void zero_tail(unsigned* __restrict__ p) {
  p[blockIdx.x * 256 + threadIdx.x] = 0u;
}

// ---------- kernel 0c: WbT rows 512..545 = (Wb @ W34)^T ----------
__global__ __launch_bounds__(256) void wfold_rows(const float* __restrict__ Wb,
                                                  const float* __restrict__ Wp,
                                                  const float* __restrict__ Ws,
                                                  unsigned short* __restrict__ WbT) {
  int w = threadIdx.x >> 6, lane = threadIdx.x & 63;
  int k = blockIdx.x * 4 + w;
  if (lane >= 34) return;
  const float* src;
  if (lane < 2) src = Wp + lane;
  else { int s = (lane - 2) >> 1; src = Ws + s * 1024 + (lane & 1); }
  const float* wrow = Wb + (long)k * DEMB;
  float acc = 0.f;
#pragma unroll 8
  for (int d = 0; d < DEMB; ++d) acc = fmaf(wrow[d], src[2 * d], acc);
  WbT[(long)(512 + lane) * DIN + k] = f2bf(acc);
}

// ---------- kernel 0d: bfold[j] = bb @ W34[:,j] + bias34[j] ----------
__global__ void bfold_k(const float* __restrict__ bb, const float* __restrict__ Wp,
                        const float* __restrict__ bp, const float* __restrict__ Ws,
                        const float* __restrict__ bs, float* __restrict__ bf) {
  int j = threadIdx.x;
  if (j >= 34) return;
  const float* src; float bias;
  if (j < 2) { src = Wp + j; bias = bp[j]; }
  else { int s = (j - 2) >> 1; src = Ws + s * 1024 + (j & 1); bias = bs[s * 2 + (j & 1)]; }
  float acc = bias;
  for (int d = 0; d < DEMB; ++d) acc = fmaf(bb[d], src[2 * d], acc);
  bf[j] = acc;
}

#define SB __builtin_amdgcn_sched_barrier(0)

// ---------- kernel 1: fused GEMM — R13 + B 2-deep (3 slots), ONE wait/phase ----------
// 128x128 tile, BK=64, 2x2 waves. Phase t: stage B(t+2) [Bs (t+2)%3]; load
// A(t+2) regs; compute(t) [16 ds_read + 32 MFMA]; vmcnt(12) drains exactly
// {B(t+1), A(t+1)} (both issued >=1 full phase ago — no latency exposure);
// writeA(t+1); lgkm0; barrier. R13's post-compute vmcnt(8) B-stall removed.
__global__ __launch_bounds__(256, 2) void gemm_fused(
    const float* __restrict__ x, const unsigned short* __restrict__ wbt,
    const float* __restrict__ bb, const int* __restrict__ sid,
    const float* __restrict__ bfold, float* __restrict__ out) {
  __shared__ __align__(16) char SM[81920];   // As0|As1 (16K) | Bs0|Bs1|Bs2 (16K)
  char* const As0 = SM;
  char* const As1 = SM + 16384;
  char* const Bs0 = SM + 32768;
  char* const Bs1 = SM + 49152;
  char* const Bs2 = SM + 65536;

  const int t = threadIdx.x;
  const int lane = t & 63;
  const int wid = t >> 6;
  const int wm = wid >> 1, wn = wid & 1;

  // XCD swizzle: 5120 blocks (%8==0); 5 consecutive swz share one mtile/XCD.
  const int bid = blockIdx.x;
  const int swz = (bid & 7) * 640 + (bid >> 3);
  const int mtile = swz / 5;
  const int ntile = swz - mtile * 5;         // 0..3 emb, 4 = head
  const long m0 = (long)mtile * 128;
  const int n0 = ntile * 128;

  // ---- A staging (R13-verbatim): row = t>>4 (+p*16), 16B-col t&15 ----
  const int arow = t >> 4;
  const int acol8 = (t & 15) * 8;
  const int abyte = arow * 128 + (acol8 ^ ((arow & 7) << 4));   // +p*2048
  const float* xbase = x + (m0 + arow) * DIN + (t & 15) * 4;

  // ---- B staging (R13-verbatim): gload_lds, pre-swizzled source ----
  const int bn = wid * 32 + (lane >> 3);
  const int bg = (lane & 7) ^ (lane >> 3);
  const unsigned short* bsrc = wbt + (long)(n0 + bn) * DIN + bg * 8;

  // ---- fragment reads (R13-verbatim): granule (ks*4+lg) ^ (l15&7), 128B rows ----
  const int l15 = lane & 15, lg = lane >> 4;
  const int s3 = lane & 7;
  const int kg0 = ((lg ^ s3) << 4);
  const int ardrow = (wm * 64 + l15) * 128;
  const int brdrow = (wn * 64 + l15) * 128;

  f32x4 acc[4][4] = {};
  float4 aA[8], aB[8];                       // A(k): k even -> aA, k odd -> aB

  auto loadA = [&](float4* d, int k0) {
#pragma unroll
    for (int p = 0; p < 8; ++p)
      d[p] = *(const float4*)(xbase + (long)p * 16 * DIN + k0);
  };
  auto stageB = [&](char* Bw, int k0) {
#pragma unroll
    for (int i = 0; i < 4; ++i) {
      const unsigned short* gp = bsrc + (long)i * 8 * DIN + k0;
      __builtin_amdgcn_global_load_lds(
          (const __attribute__((address_space(1))) void*)gp,
          (__attribute__((address_space(3))) void*)(Bw + wid * 4096 + i * 1024),
          16, 0, 0);
    }
  };
  auto writeA = [&](char* Aw, const float4* d) {
#pragma unroll
    for (int p = 0; p < 8; ++p) {
      uint2 v;
      v.x = pkhi(d[p].x, d[p].y);
      v.y = pkhi(d[p].z, d[p].w);
      *(uint2*)(Aw + abyte + p * 2048) = v;
    }
  };
  auto compute = [&](const char* Ac, const char* Bc) {   // 16 ds_read + 32 MFMA
#pragma unroll
    for (int ks = 0; ks < 2; ++ks) {
      const int kgo = kg0 ^ (ks << 6);
      bf16x8 af[4], bfv[4];
#pragma unroll
      for (int i = 0; i < 4; ++i) {
        af[i]  = *(const bf16x8*)(Ac + ardrow + i * 2048 + kgo);
        bfv[i] = *(const bf16x8*)(Bc + brdrow + i * 2048 + kgo);
      }
      __builtin_amdgcn_s_setprio(1);
#pragma unroll
      for (int mi = 0; mi < 4; ++mi)
#pragma unroll
        for (int ni = 0; ni < 4; ++ni)
          acc[mi][ni] = __builtin_amdgcn_mfma_f32_16x16x32_bf16(af[mi], bfv[ni],
                                                               acc[mi][ni], 0, 0, 0);
      __builtin_amdgcn_s_setprio(0);
    }
  };

  // phase t: stage B(t+2); load A(t+2); compute(t); vmcnt(12) [{B(t+1),A(t+1)}
  // done — both issued at phase t-1]; writeA(A(t+1)); lgkm0; barrier.
#define PH(BC, BST, AC, ALD, AWS, AWB, TT)                          \
  stageB(BST, ((TT) + 2) * 64);                                     \
  loadA(ALD, ((TT) + 2) * 64);                                      \
  compute(AC, BC);                                                  \
  SB; asm volatile("s_waitcnt vmcnt(12)" ::: "memory"); SB;         \
  writeA(AWS, AWB);                                                 \
  SB; asm volatile("s_waitcnt lgkmcnt(0)" ::: "memory"); SB;        \
  __builtin_amdgcn_s_barrier();

  // ---- prologue: B(0),B(1),A(0),A(1) issued; A(0) written ----
  stageB(Bs0, 0);
  stageB(Bs1, 64);
  loadA(aA, 0);
  loadA(aB, 64);
  SB; asm volatile("s_waitcnt vmcnt(8)" ::: "memory"); SB;   // B0,B1,A0 done; A1 flying
  writeA(As0, aA);
  SB; asm volatile("s_waitcnt lgkmcnt(0)" ::: "memory"); SB;
  __builtin_amdgcn_s_barrier();

  // ---- main loop: phases 0..11 (period-6), then 12,13 explicit ----
#pragma unroll 1
  for (int tb = 0; tb < 12; tb += 6) {
    PH(Bs0, Bs2, As0, aA, As1, aB, tb + 0)
    PH(Bs1, Bs0, As1, aB, As0, aA, tb + 1)
    PH(Bs2, Bs1, As0, aA, As1, aB, tb + 2)
    PH(Bs0, Bs2, As1, aB, As0, aA, tb + 3)
    PH(Bs1, Bs0, As0, aA, As1, aB, tb + 4)
    PH(Bs2, Bs1, As1, aB, As0, aA, tb + 5)
  }
  PH(Bs0, Bs2, As0, aA, As1, aB, 12)
  PH(Bs1, Bs0, As1, aB, As0, aA, 13)
#undef PH

  // ---- phase 14: no issues; compute 14 (Bs2); drain; write A(15) ----
  compute(As0, Bs2);
  SB; asm volatile("s_waitcnt vmcnt(0)" ::: "memory"); SB;   // B(15)+A(15) done
  writeA(As1, aB);
  SB; asm volatile("s_waitcnt lgkmcnt(0)" ::: "memory"); SB;
  __builtin_amdgcn_s_barrier();
  // ---- phase 15 ----
  compute(As1, Bs0);                                         // 15%3 = 0

  // ---- epilogue (R13-verbatim) ----
  if (ntile < 4) {
    const int colg = n0 + wn * 64 + l15;
    float bbv[4];
#pragma unroll
    for (int ni = 0; ni < 4; ++ni) bbv[ni] = bb[colg + ni * 16];
#pragma unroll
    for (int mi = 0; mi < 4; ++mi) {
      const long rbase = m0 + wm * 64 + mi * 16 + lg * 4;
#pragma unroll
      for (int ni = 0; ni < 4; ++ni)
#pragma unroll
        for (int r = 0; r < 4; ++r)
          out[(rbase + r) * DEMB + colg + ni * 16] = acc[mi][ni][r] + bbv[ni];
    }
  } else {
    // head tile: acc cols 0..33 are x@Wfold; gather per-row selected cols via LDS
    __syncthreads();
    float* hl = (float*)SM;                  // [128][35] f32 = 17.5 KiB overlay
    if (wn == 0) {
#pragma unroll
      for (int ni = 0; ni < 3; ++ni) {
#pragma unroll
        for (int mi = 0; mi < 4; ++mi)
#pragma unroll
          for (int r = 0; r < 4; ++r) {
            int row = wm * 64 + mi * 16 + lg * 4 + r;
            int col = l15 + ni * 16;
            if (col < 35) hl[row * 35 + col] = acc[mi][ni][r];
          }
      }
    }
    __syncthreads();
    if (t < 128) {
      const long row = m0 + t;
      const int s = sid[row];
      const float v0 = hl[t * 35 + 0] + bfold[0];
      const float v1 = hl[t * 35 + 1] + bfold[1];
      const float v2 = hl[t * 35 + 2 + 2 * s] + bfold[2 + 2 * s];
      const float v3 = hl[t * 35 + 3 + 2 * s] + bfold[3 + 2 * s];
      float* hp = out + NROWS * DEMB;
      hp[row] = v0;
      hp[NROWS + row] = softplusf(v1) + 0.001f;
      hp[2 * NROWS + row] = v2;
      hp[3 * NROWS + row] = softplusf(v3) + 0.001f;
    }
  }
}

extern "C" void kernel_launch(void* const* d_in, const int* in_sizes, int n_in,
                              void* d_out, int out_size, void* d_ws, size_t ws_size,
                              hipStream_t stream) {
  const float* x  = (const float*)d_in[0];
  const int* sid  = (const int*)d_in[1];
  const float* Wb = (const float*)d_in[2];
  const float* bb = (const float*)d_in[3];
  const float* Wp = (const float*)d_in[4];
  const float* bp = (const float*)d_in[5];
  const float* Ws = (const float*)d_in[6];
  const float* bs = (const float*)d_in[7];
  float* out = (float*)d_out;
  unsigned short* WbT = (unsigned short*)d_ws;            // 640*1024 bf16 = 1.25 MiB
  float* bfoldp = (float*)(WbT + (long)NEXT * DIN);       // 34 f32

  wb_transpose<<<256, 256, 0, stream>>>(Wb, WbT);
  zero_tail<<<188, 256, 0, stream>>>((unsigned*)(WbT + 546 * DIN));
  wfold_rows<<<256, 256, 0, stream>>>(Wb, Wp, Ws, WbT);
  bfold_k<<<1, 64, 0, stream>>>(bb, Wp, bp, Ws, bs, bfoldp);
  gemm_fused<<<5120, 256, 0, stream>>>(x, WbT, bb, sid, bfoldp, out);
}